// Round 18
// baseline (128.859 us; speedup 1.0000x reference)
//
#include <hip/hip_runtime.h>
#include <float.h>

#define NT 32768
#define DIM 2048
#define NE 64
#define TAU 1e-3f

typedef __attribute__((ext_vector_type(8))) short short8;
typedef __attribute__((ext_vector_type(4))) float f32x4;

__device__ __forceinline__ unsigned short f2bf(float f) {
    unsigned u = __float_as_uint(f);
    u += 0x7fffu + ((u >> 16) & 1u);          // RNE
    return (unsigned short)(u >> 16);
}
__device__ __forceinline__ float bf2f(unsigned short h) {
    return __uint_as_float(((unsigned)h) << 16);
}

// Pack gw into MFMA-B fragment order, hi/lo interleaved 32B records:
// wpk[((et*64 + ksg)*64 + lane)*16 + {0..7 hi, 8..15 lo}]
//   = split of gw[et*16 + (lane&15)][ksg*32 + (lane>>4)*8 + j]
__global__ __launch_bounds__(256)
void prep_w(const float* __restrict__ gw, unsigned short* __restrict__ wpk,
            int* __restrict__ cnt) {
    const int gid  = blockIdx.x * 256 + threadIdx.x;   // 16384 threads
    const int lane = gid & 63;
    const int ksg  = (gid >> 6) & 63;
    const int et   = gid >> 12;
    const int e    = et * 16 + (lane & 15);
    const int k0   = ksg * 32 + (lane >> 4) * 8;

    float4 v0 = *(const float4*)(gw + (size_t)e * DIM + k0);
    float4 v1 = *(const float4*)(gw + (size_t)e * DIM + k0 + 4);
    float xf[8] = {v0.x, v0.y, v0.z, v0.w, v1.x, v1.y, v1.z, v1.w};
    short8 h, l;
#pragma unroll
    for (int j = 0; j < 8; ++j) {
        unsigned short hh = f2bf(xf[j]);
        h[j] = (short)hh;
        l[j] = (short)f2bf(xf[j] - bf2f(hh));
    }
    *(short8*)(wpk + (size_t)gid * 16)     = h;
    *(short8*)(wpk + (size_t)gid * 16 + 8) = l;
    if (gid == 0) *cnt = 0;
}

__global__ __launch_bounds__(256, 4)
void router_mfma(const float* __restrict__ x,
                 const unsigned short* __restrict__ wpk,
                 float* __restrict__ out,
                 int* __restrict__ cnt, int* __restrict__ list) {
    const int tid  = threadIdx.x;
    const int lane = tid & 63;
    const int wid  = tid >> 6;
    const int t0   = (blockIdx.x * 4 + wid) * 16;   // 16 tokens per wave

    // A-frag addressing: row = lane&15 (token), kg = lane>>4 (k-octet)
    const float* xp = x + (size_t)(t0 + (lane & 15)) * DIM + (lane >> 4) * 8;
    // B pointers: 4 expert-tiles, hi at +0 / lo at +8 shorts of each 32B record
    const unsigned short* wp0 = wpk + (size_t)lane * 16;
    const unsigned short* wp1 = wp0 + 65536;        // et stride = 64*64*16 shorts
    const unsigned short* wp2 = wp0 + 131072;
    const unsigned short* wp3 = wp0 + 196608;

    f32x4 accP[4], accQ[4];
#pragma unroll
    for (int et = 0; et < 4; ++et)
#pragma unroll
        for (int j = 0; j < 4; ++j) { accP[et][j] = 0.f; accQ[et][j] = 0.f; }

    float4 xA0, xA1, xB0, xB1;
    short8 Bh[4], Bl[4];

#define LOADXA(off_) { xA0 = *(const float4*)(xp + (off_)); \
                       xA1 = *(const float4*)(xp + (off_) + 4); }
#define LOADXB(off_) { xB0 = *(const float4*)(xp + (off_)); \
                       xB1 = *(const float4*)(xp + (off_) + 4); }
#define BLOAD(off_) { \
        Bh[0] = *(const short8*)(wp0 + (off_)); Bl[0] = *(const short8*)(wp0 + (off_) + 8); \
        Bh[1] = *(const short8*)(wp1 + (off_)); Bl[1] = *(const short8*)(wp1 + (off_) + 8); \
        Bh[2] = *(const short8*)(wp2 + (off_)); Bl[2] = *(const short8*)(wp2 + (off_) + 8); \
        Bh[3] = *(const short8*)(wp3 + (off_)); Bl[3] = *(const short8*)(wp3 + (off_) + 8); }

// truncation split (lo.lo dropped term ~1e-5 logit error << TAU) + 12 MFMA
#define SPLIT_MFMA(v0_, v1_) { \
        float f_[8] = {v0_.x, v0_.y, v0_.z, v0_.w, v1_.x, v1_.y, v1_.z, v1_.w}; \
        short8 Ah_, Al_; \
        _Pragma("unroll") for (int j = 0; j < 8; ++j) { \
            unsigned u_ = __float_as_uint(f_[j]); \
            Ah_[j] = (short)(unsigned short)(u_ >> 16); \
            float lo_ = f_[j] - __uint_as_float(u_ & 0xffff0000u); \
            Al_[j] = (short)(unsigned short)(__float_as_uint(lo_) >> 16); } \
        _Pragma("unroll") for (int et = 0; et < 4; ++et) { \
            accP[et] = __builtin_amdgcn_mfma_f32_16x16x32_bf16(Ah_, Bh[et], accP[et], 0, 0, 0); \
            accQ[et] = __builtin_amdgcn_mfma_f32_16x16x32_bf16(Ah_, Bl[et], accQ[et], 0, 0, 0); \
            accQ[et] = __builtin_amdgcn_mfma_f32_16x16x32_bf16(Al_, Bh[et], accQ[et], 0, 0, 0); } }

    // K loop: 64 steps of K=32; even/odd x banks, B loaded per step; NO barriers
    LOADXA(0)
#pragma unroll 1
    for (int s2 = 0; s2 < 31; ++s2) {
        BLOAD(0)                 // B(even step)
        LOADXB(32)               // x(odd step)
        SPLIT_MFMA(xA0, xA1)
        BLOAD(1024)              // B(odd step)
        LOADXA(64)               // x(next even step)
        SPLIT_MFMA(xB0, xB1)
        xp += 64;                // 2 steps of 32 floats
        wp0 += 2048; wp1 += 2048; wp2 += 2048; wp3 += 2048;
    }
    // peel steps 62, 63 (banks: A holds 62 from last iter; all pointers advanced 31x)
    BLOAD(0)
    LOADXB(32)
    SPLIT_MFMA(xA0, xA1)
    BLOAD(1024)
    SPLIT_MFMA(xB0, xB1)

#undef LOADXA
#undef LOADXB
#undef BLOAD
#undef SPLIT_MFMA

    // ---- epilogue: fully in-wave. lane holds logits for token (lane>>4)*4+jr,
    //      experts et*16 + (lane&15). Merge across each 16-lane group. ----
    float* mout = out;
    float* wout = out + (size_t)NT * NE;
    float* iout = wout + (size_t)NT * 2;
    const int l15 = lane & 15;

#pragma unroll
    for (int jr = 0; jr < 4; ++jr) {
        const int tok = t0 + (lane >> 4) * 4 + jr;

        float m1 = -FLT_MAX, m2 = -FLT_MAX, m3 = -FLT_MAX;
        int   i1 = NE, i2 = NE, i3 = NE;
        auto ins = [&](float v, int e) {
            bool b1 = (v > m1) || (v == m1 && e < i1);
            bool b2 = (v > m2) || (v == m2 && e < i2);
            bool b3 = (v > m3) || (v == m3 && e < i3);
            if (b1)      { m3 = m2; i3 = i2; m2 = m1; i2 = i1; m1 = v; i1 = e; }
            else if (b2) { m3 = m2; i3 = i2; m2 = v; i2 = e; }
            else if (b3) { m3 = v; i3 = e; }
        };
        ins(accP[0][jr] + accQ[0][jr], l15);
        ins(accP[1][jr] + accQ[1][jr], 16 + l15);
        ins(accP[2][jr] + accQ[2][jr], 32 + l15);
        ins(accP[3][jr] + accQ[3][jr], 48 + l15);
#pragma unroll
        for (int off = 1; off <= 8; off <<= 1) {   // merge within 16-lane group
            float om1 = __shfl_xor(m1, off, 64); int oi1 = __shfl_xor(i1, off, 64);
            float om2 = __shfl_xor(m2, off, 64); int oi2 = __shfl_xor(i2, off, 64);
            float om3 = __shfl_xor(m3, off, 64); int oi3 = __shfl_xor(i3, off, 64);
            ins(om1, oi1); ins(om2, oi2); ins(om3, oi3);
        }

        float ed  = expf(m2 - m1);
        float inv = 1.f / (1.f + ed);

#pragma unroll
        for (int et = 0; et < 4; ++et) {
            int e = et * 16 + l15;
            mout[(size_t)tok * NE + e] = (e == i1 || e == i2) ? 1.f : 0.f;
        }
        if (l15 == 0) {
            *(float2*)(wout + 2 * tok) = make_float2(inv, ed * inv);
            *(float2*)(iout + 2 * tok) = make_float2((float)i1, (float)i2);
            if ((m1 - m2 < TAU) || (m2 - m3 < TAU)) {
                int slot = atomicAdd(cnt, 1);
                list[slot] = tok;
            }
        }
    }
}

// Exact fp32 recompute of flagged (near-tie) tokens; overwrites their outputs.
__global__ __launch_bounds__(256)
void repair(const float* __restrict__ x, const float* __restrict__ gw,
            float* __restrict__ out, const int* __restrict__ cnt,
            const int* __restrict__ list) {
    __shared__ float red[64][5];
    const int n   = *cnt;
    const int tid = threadIdx.x;
    const int e   = tid & 63, qq = tid >> 6;     // expert, k-quarter

    float* mout = out;
    float* wout = out + (size_t)NT * NE;
    float* iout = wout + (size_t)NT * 2;

    for (int i = blockIdx.x; i < n; i += gridDim.x) {
        const int tok = list[i];
        const float* xr = x + (size_t)tok * DIM + qq * 512;
        const float* wr = gw + (size_t)e * DIM + qq * 512;
        float a = 0.f;
        for (int j = 0; j < 512; j += 4) {
            float4 xv = *(const float4*)(xr + j);
            float4 wv = *(const float4*)(wr + j);
            a = fmaf(xv.x, wv.x, a); a = fmaf(xv.y, wv.y, a);
            a = fmaf(xv.z, wv.z, a); a = fmaf(xv.w, wv.w, a);
        }
        red[e][qq] = a;
        __syncthreads();
        if (tid < 64) {
            float v = ((red[e][0] + red[e][1]) + red[e][2]) + red[e][3];
            float m1 = v, m2 = -FLT_MAX; int i1 = e, i2 = NE;
#pragma unroll
            for (int off = 1; off <= 32; off <<= 1) {
                float om1 = __shfl_xor(m1, off, 64); int oi1 = __shfl_xor(i1, off, 64);
                float om2 = __shfl_xor(m2, off, 64); int oi2 = __shfl_xor(i2, off, 64);
                bool selfFirst = (m1 > om1) || (m1 == om1 && i1 < oi1);
                if (selfFirst) {
                    if (!((m2 > om1) || (m2 == om1 && i2 < oi1))) { m2 = om1; i2 = oi1; }
                } else {
                    bool c = (m1 > om2) || (m1 == om2 && i1 < oi2);
                    if (c) { m2 = m1; i2 = i1; } else { m2 = om2; i2 = oi2; }
                    m1 = om1; i1 = oi1;
                }
            }
            float ed  = expf(m2 - m1);
            float inv = 1.f / (1.f + ed);
            mout[(size_t)tok * NE + e] = (e == i1 || e == i2) ? 1.f : 0.f;
            if (e == 0) {
                *(float2*)(wout + 2 * tok) = make_float2(inv, ed * inv);
                *(float2*)(iout + 2 * tok) = make_float2((float)i1, (float)i2);
            }
        }
        __syncthreads();
    }
}

extern "C" void kernel_launch(void* const* d_in, const int* in_sizes, int n_in,
                              void* d_out, int out_size, void* d_ws, size_t ws_size,
                              hipStream_t stream) {
    const float* x  = (const float*)d_in[0];
    const float* gw = (const float*)d_in[1];
    float* out = (float*)d_out;

    unsigned short* wpk = (unsigned short*)d_ws;         // 512 KB packed hi|lo
    int* cnt  = (int*)(wpk + 262144);                    // 4 B
    int* list = cnt + 1;                                 // 128 KB

    prep_w<<<dim3(64), dim3(256), 0, stream>>>(gw, wpk, cnt);
    router_mfma<<<dim3(NT / 64), dim3(256), 0, stream>>>(x, wpk, out, cnt, list);
    repair<<<dim3(256), dim3(256), 0, stream>>>(x, gw, out, cnt, list);
}

// Round 19
// 117.385 us; speedup vs baseline: 1.0977x; 1.0977x over previous
//
#include <hip/hip_runtime.h>
#include <float.h>

#define NT 32768
#define DIM 2048
#define NE 64
#define TAU 1e-3f
#define CHUNK 128
#define NCH (DIM / CHUNK)   // 16 chunks

typedef __attribute__((ext_vector_type(8))) short short8;
typedef __attribute__((ext_vector_type(4))) float f32x4;

__device__ __forceinline__ unsigned short f2bf(float f) {
    unsigned u = __float_as_uint(f);
    u += 0x7fffu + ((u >> 16) & 1u);          // RNE
    return (unsigned short)(u >> 16);
}
__device__ __forceinline__ float bf2f(unsigned short h) {
    return __uint_as_float(((unsigned)h) << 16);
}

// Pack gw into MFMA-B fragment order, split hi/lo bf16 (RNE):
// wpk[et][ksg][lane][j] = gw[et*16 + (lane&15)][ksg*32 + (lane>>4)*8 + j]
__global__ __launch_bounds__(256)
void prep_w(const float* __restrict__ gw, unsigned short* __restrict__ wph,
            unsigned short* __restrict__ wpl, int* __restrict__ cnt) {
    const int gid  = blockIdx.x * 256 + threadIdx.x;   // 16384 threads
    const int lane = gid & 63;
    const int ksg  = (gid >> 6) & 63;
    const int et   = gid >> 12;
    const int e    = et * 16 + (lane & 15);
    const int k0   = ksg * 32 + (lane >> 4) * 8;

    float4 v0 = *(const float4*)(gw + (size_t)e * DIM + k0);
    float4 v1 = *(const float4*)(gw + (size_t)e * DIM + k0 + 4);
    float xf[8] = {v0.x, v0.y, v0.z, v0.w, v1.x, v1.y, v1.z, v1.w};
    short8 h, l;
#pragma unroll
    for (int j = 0; j < 8; ++j) {
        unsigned short hh = f2bf(xf[j]);
        h[j] = (short)hh;
        l[j] = (short)f2bf(xf[j] - bf2f(hh));
    }
    *(short8*)(wph + (size_t)gid * 8) = h;
    *(short8*)(wpl + (size_t)gid * 8) = l;
    if (gid == 0) *cnt = 0;
}

__global__ __launch_bounds__(256, 2)
void router_mfma(const float* __restrict__ x,
                 const unsigned short* __restrict__ wph,
                 const unsigned short* __restrict__ wpl,
                 float* __restrict__ out,
                 int* __restrict__ cnt, int* __restrict__ list) {
    // 64 KB: 2 dbuf x {hi plane 16K, lo plane 16K}; epilogue aliases float lm[64][68]
    __shared__ __align__(16) unsigned char smem[65536];

    const int tid  = threadIdx.x;
    const int lane = tid & 63;
    const int et   = tid >> 6;                 // wave == 16-expert tile
    const int t0   = blockIdx.x * 64;

    // staging coords: thread (sr = token row 0..15, sq = k-quad 0..15)
    const int sr = tid >> 4;
    const int sq = tid & 15;
    const unsigned swoff = (unsigned)((sr * 128 + sq * 8) ^ ((sr & 7) << 4));
    const float* xbase = x + (size_t)(t0 + sr) * DIM + sq * 4;

    // compute-side swizzled read offsets (ks even / odd)
    const unsigned roff_e = (unsigned)((((lane & 15) * 128) | ((lane >> 4) << 4))
                                       ^ ((lane & 7) << 4));
    const unsigned roff_o = roff_e ^ 64u;

    f32x4 accP[4], accQ[4];
#pragma unroll
    for (int tt = 0; tt < 4; ++tt)
#pragma unroll
        for (int j = 0; j < 4; ++j) { accP[tt][j] = 0.f; accQ[tt][j] = 0.f; }

    float4 xrA[8], xrB[8];                     // depth-2 x prefetch banks
    short8 Bh0[4], Bl0[4], Bh1[4], Bl1[4];

#define LOADX(bank_, c_) { _Pragma("unroll") for (int tt = 0; tt < 4; ++tt) \
    _Pragma("unroll") for (int i = 0; i < 2; ++i) \
        xr##bank_[tt*2+i] = *(const float4*)(xbase + (size_t)tt * 16 * DIM + (c_) * CHUNK + i * 64); }

#define BLOAD(bk_, c_) { _Pragma("unroll") for (int ksg = 0; ksg < 4; ++ksg) { \
        size_t o_ = (((size_t)et * 64 + ((c_) * 4 + ksg)) * 64 + lane) * 8; \
        Bh##bk_[ksg] = *(const short8*)(wph + o_); \
        Bl##bk_[ksg] = *(const short8*)(wpl + o_); } }

// truncation split: hi = top16(x), lo = top16(x - hi)
#define CVT_STORE(bank_, buf_) { _Pragma("unroll") for (int tt = 0; tt < 4; ++tt) \
    _Pragma("unroll") for (int i = 0; i < 2; ++i) { \
        float4 v_ = xr##bank_[tt*2+i]; \
        unsigned u0 = __float_as_uint(v_.x), u1 = __float_as_uint(v_.y); \
        unsigned u2 = __float_as_uint(v_.z), u3 = __float_as_uint(v_.w); \
        float l0 = v_.x - __uint_as_float(u0 & 0xffff0000u); \
        float l1 = v_.y - __uint_as_float(u1 & 0xffff0000u); \
        float l2 = v_.z - __uint_as_float(u2 & 0xffff0000u); \
        float l3 = v_.w - __uint_as_float(u3 & 0xffff0000u); \
        ushort4 hv_ = make_ushort4((unsigned short)(u0 >> 16), (unsigned short)(u1 >> 16), \
                                   (unsigned short)(u2 >> 16), (unsigned short)(u3 >> 16)); \
        ushort4 lv_ = make_ushort4((unsigned short)(__float_as_uint(l0) >> 16), \
                                   (unsigned short)(__float_as_uint(l1) >> 16), \
                                   (unsigned short)(__float_as_uint(l2) >> 16), \
                                   (unsigned short)(__float_as_uint(l3) >> 16)); \
        unsigned char* p_ = smem + (buf_) * 32768 + (tt*2+i) * 2048 + swoff; \
        *(ushort4*)p_ = hv_; \
        *(ushort4*)(p_ + 16384) = lv_; } }

#define MFMA_PHASE(buf_, bk_) { \
        __builtin_amdgcn_s_setprio(1); \
        _Pragma("unroll") for (int ks = 0; ks < 4; ++ks) { \
        const unsigned ro_ = (ks & 1) ? roff_o : roff_e; \
        _Pragma("unroll") for (int tt = 0; tt < 4; ++tt) { \
            const unsigned char* pa_ = smem + (buf_) * 32768 + tt * 4096 + (ks >> 1) * 2048 + ro_; \
            short8 Ah_ = *(const short8*)pa_; \
            short8 Al_ = *(const short8*)(pa_ + 16384); \
            accP[tt] = __builtin_amdgcn_mfma_f32_16x16x32_bf16(Ah_, Bh##bk_[ks], accP[tt], 0, 0, 0); \
            accQ[tt] = __builtin_amdgcn_mfma_f32_16x16x32_bf16(Ah_, Bl##bk_[ks], accQ[tt], 0, 0, 0); \
            accQ[tt] = __builtin_amdgcn_mfma_f32_16x16x32_bf16(Al_, Bh##bk_[ks], accQ[tt], 0, 0, 0); } } \
        __builtin_amdgcn_s_setprio(0); }

// T3/T4: LDS-only wait + raw barrier -> global prefetches stay in flight
#define BARSYNC { asm volatile("s_waitcnt lgkmcnt(0)" ::: "memory"); \
                  __builtin_amdgcn_sched_barrier(0); \
                  __builtin_amdgcn_s_barrier(); }

    // prologue: chunks 0,1 in flight; chunk 0 staged; B(0) in bank 0
    BLOAD(0, 0)
    LOADX(A, 0)
    LOADX(B, 1)
    CVT_STORE(A, 0)
    BARSYNC

    // steady state: c = 0..13, branch-free bodies (7 even/odd pairs)
#pragma unroll 1
    for (int cc = 0; cc < 7; ++cc) {
        const int c0 = 2 * cc;                 // even chunk, c0 <= 12
        BLOAD(1, c0 + 1)
        LOADX(A, c0 + 2)
        MFMA_PHASE(0, 0)
        CVT_STORE(B, 1)
        BARSYNC
        const int c1 = c0 + 1;                 // odd chunk, c1 <= 13
        BLOAD(0, c1 + 1)
        LOADX(B, c1 + 2)
        MFMA_PHASE(1, 1)
        CVT_STORE(A, 0)
        BARSYNC
    }
    // tail c = 14: no LOADX (bank B already holds chunk 15 from the last pair)
    BLOAD(1, 15)
    MFMA_PHASE(0, 0)
    CVT_STORE(B, 1)
    BARSYNC
    // tail c = 15: MFMA only
    MFMA_PHASE(1, 1)

#undef LOADX
#undef BLOAD
#undef CVT_STORE
#undef MFMA_PHASE
#undef BARSYNC

    // merge logits into aliased LDS (buf0 region last read before previous barrier)
    float* lmf = (float*)smem;                 // [64][68]
#pragma unroll
    for (int tt = 0; tt < 4; ++tt)
#pragma unroll
        for (int jr = 0; jr < 4; ++jr)
            lmf[(tt * 16 + (lane >> 4) * 4 + jr) * 68 + et * 16 + (lane & 15)] =
                accP[tt][jr] + accQ[tt][jr];
    __syncthreads();

    // ---- epilogue: 4 threads per token, 16 experts each ----
    float* mout = out;
    float* wout = out + (size_t)NT * NE;
    float* iout = wout + (size_t)NT * 2;

    const int t   = tid >> 2;                  // local token 0..63
    const int s   = tid & 3;                   // 16-expert segment
    const int tok = t0 + t;

    float vv[16];
#pragma unroll
    for (int j4 = 0; j4 < 4; ++j4) {
        float4 pv = *(const float4*)&lmf[t * 68 + s * 16 + j4 * 4];
        vv[j4 * 4] = pv.x; vv[j4 * 4 + 1] = pv.y; vv[j4 * 4 + 2] = pv.z; vv[j4 * 4 + 3] = pv.w;
    }

    float m1 = -FLT_MAX, m2 = -FLT_MAX, m3 = -FLT_MAX;
    int   i1 = NE, i2 = NE, i3 = NE;
    auto ins = [&](float v, int e) {
        bool b1 = (v > m1) || (v == m1 && e < i1);
        bool b2 = (v > m2) || (v == m2 && e < i2);
        bool b3 = (v > m3) || (v == m3 && e < i3);
        if (b1)      { m3 = m2; i3 = i2; m2 = m1; i2 = i1; m1 = v; i1 = e; }
        else if (b2) { m3 = m2; i3 = i2; m2 = v; i2 = e; }
        else if (b3) { m3 = v; i3 = e; }
    };
#pragma unroll
    for (int j = 0; j < 16; ++j) ins(vv[j], s * 16 + j);
#pragma unroll
    for (int off = 1; off <= 2; off <<= 1) {   // merge across the 4-lane group
        float om1 = __shfl_xor(m1, off, 64); int oi1 = __shfl_xor(i1, off, 64);
        float om2 = __shfl_xor(m2, off, 64); int oi2 = __shfl_xor(i2, off, 64);
        float om3 = __shfl_xor(m3, off, 64); int oi3 = __shfl_xor(i3, off, 64);
        ins(om1, oi1); ins(om2, oi2); ins(om3, oi3);
    }

    float ed  = expf(m2 - m1);
    float inv = 1.f / (1.f + ed);

#pragma unroll
    for (int j4 = 0; j4 < 4; ++j4) {
        float4 mv;
        int e0 = s * 16 + j4 * 4;
        mv.x = (e0     == i1 || e0     == i2) ? 1.f : 0.f;
        mv.y = (e0 + 1 == i1 || e0 + 1 == i2) ? 1.f : 0.f;
        mv.z = (e0 + 2 == i1 || e0 + 2 == i2) ? 1.f : 0.f;
        mv.w = (e0 + 3 == i1 || e0 + 3 == i2) ? 1.f : 0.f;
        *(float4*)(mout + (size_t)tok * NE + e0) = mv;
    }

    if (s == 0) {
        *(float2*)(wout + 2 * tok) = make_float2(inv, ed * inv);
        *(float2*)(iout + 2 * tok) = make_float2((float)i1, (float)i2);
        if ((m1 - m2 < TAU) || (m2 - m3 < TAU)) {
            int slot = atomicAdd(cnt, 1);
            list[slot] = tok;
        }
    }
}

// Exact fp32 recompute of flagged (near-tie) tokens; overwrites their outputs.
__global__ __launch_bounds__(256)
void repair(const float* __restrict__ x, const float* __restrict__ gw,
            float* __restrict__ out, const int* __restrict__ cnt,
            const int* __restrict__ list) {
    __shared__ float red[64][5];
    const int n   = *cnt;
    const int tid = threadIdx.x;
    const int e   = tid & 63, qq = tid >> 6;     // expert, k-quarter

    float* mout = out;
    float* wout = out + (size_t)NT * NE;
    float* iout = wout + (size_t)NT * 2;

    for (int i = blockIdx.x; i < n; i += gridDim.x) {
        const int tok = list[i];
        const float* xr = x + (size_t)tok * DIM + qq * 512;
        const float* wr = gw + (size_t)e * DIM + qq * 512;
        float a = 0.f;
        for (int j = 0; j < 512; j += 4) {
            float4 xv = *(const float4*)(xr + j);
            float4 wv = *(const float4*)(wr + j);
            a = fmaf(xv.x, wv.x, a); a = fmaf(xv.y, wv.y, a);
            a = fmaf(xv.z, wv.z, a); a = fmaf(xv.w, wv.w, a);
        }
        red[e][qq] = a;
        __syncthreads();
        if (tid < 64) {
            float v = ((red[e][0] + red[e][1]) + red[e][2]) + red[e][3];
            float m1 = v, m2 = -FLT_MAX; int i1 = e, i2 = NE;
#pragma unroll
            for (int off = 1; off <= 32; off <<= 1) {
                float om1 = __shfl_xor(m1, off, 64); int oi1 = __shfl_xor(i1, off, 64);
                float om2 = __shfl_xor(m2, off, 64); int oi2 = __shfl_xor(i2, off, 64);
                bool selfFirst = (m1 > om1) || (m1 == om1 && i1 < oi1);
                if (selfFirst) {
                    if (!((m2 > om1) || (m2 == om1 && i2 < oi1))) { m2 = om1; i2 = oi1; }
                } else {
                    bool c = (m1 > om2) || (m1 == om2 && i1 < oi2);
                    if (c) { m2 = m1; i2 = i1; } else { m2 = om2; i2 = oi2; }
                    m1 = om1; i1 = oi1;
                }
            }
            float ed  = expf(m2 - m1);
            float inv = 1.f / (1.f + ed);
            mout[(size_t)tok * NE + e] = (e == i1 || e == i2) ? 1.f : 0.f;
            if (e == 0) {
                *(float2*)(wout + 2 * tok) = make_float2(inv, ed * inv);
                *(float2*)(iout + 2 * tok) = make_float2((float)i1, (float)i2);
            }
        }
        __syncthreads();
    }
}

extern "C" void kernel_launch(void* const* d_in, const int* in_sizes, int n_in,
                              void* d_out, int out_size, void* d_ws, size_t ws_size,
                              hipStream_t stream) {
    const float* x  = (const float*)d_in[0];
    const float* gw = (const float*)d_in[1];
    float* out = (float*)d_out;

    unsigned short* wph = (unsigned short*)d_ws;         // 256 KB (packed hi)
    unsigned short* wpl = wph + (size_t)NE * DIM;        // 256 KB (packed lo)
    int* cnt  = (int*)(wpl + (size_t)NE * DIM);          // 4 B
    int* list = cnt + 1;                                 // 128 KB

    prep_w<<<dim3(64), dim3(256), 0, stream>>>(gw, wph, wpl, cnt);
    router_mfma<<<dim3(NT / 64), dim3(256), 0, stream>>>(x, wph, wpl, out, cnt, list);
    repair<<<dim3(256), dim3(256), 0, stream>>>(x, gw, out, cnt, list);
}

// Round 20
// 94.310 us; speedup vs baseline: 1.3663x; 1.2447x over previous
//
#include <hip/hip_runtime.h>
#include <float.h>

#define NT 32768
#define DIM 2048
#define NE 64
#define TAU 1e-3f
#define CHUNK 128
#define NCH (DIM / CHUNK)   // 16 chunks

typedef __attribute__((ext_vector_type(8))) short short8;
typedef __attribute__((ext_vector_type(4))) float f32x4;

__device__ __forceinline__ unsigned short f2bf(float f) {
    unsigned u = __float_as_uint(f);
    u += 0x7fffu + ((u >> 16) & 1u);          // RNE
    return (unsigned short)(u >> 16);
}
__device__ __forceinline__ float bf2f(unsigned short h) {
    return __uint_as_float(((unsigned)h) << 16);
}

// Pack gw into MFMA-B fragment order, split hi/lo bf16 (RNE):
// wpk[et][ksg][lane][j] = gw[et*16 + (lane&15)][ksg*32 + (lane>>4)*8 + j]
__global__ __launch_bounds__(256)
void prep_w(const float* __restrict__ gw, unsigned short* __restrict__ wph,
            unsigned short* __restrict__ wpl, int* __restrict__ cnt) {
    const int gid  = blockIdx.x * 256 + threadIdx.x;   // 16384 threads
    const int lane = gid & 63;
    const int ksg  = (gid >> 6) & 63;
    const int et   = gid >> 12;
    const int e    = et * 16 + (lane & 15);
    const int k0   = ksg * 32 + (lane >> 4) * 8;

    float4 v0 = *(const float4*)(gw + (size_t)e * DIM + k0);
    float4 v1 = *(const float4*)(gw + (size_t)e * DIM + k0 + 4);
    float xf[8] = {v0.x, v0.y, v0.z, v0.w, v1.x, v1.y, v1.z, v1.w};
    short8 h, l;
#pragma unroll
    for (int j = 0; j < 8; ++j) {
        unsigned short hh = f2bf(xf[j]);
        h[j] = (short)hh;
        l[j] = (short)f2bf(xf[j] - bf2f(hh));
    }
    *(short8*)(wph + (size_t)gid * 8) = h;
    *(short8*)(wpl + (size_t)gid * 8) = l;
    if (gid == 0) *cnt = 0;
}

__global__ __launch_bounds__(256, 2)
void router_mfma(const float* __restrict__ x,
                 const unsigned short* __restrict__ wph,
                 const unsigned short* __restrict__ wpl,
                 float* __restrict__ out,
                 int* __restrict__ cnt, int* __restrict__ list) {
    // 64 KB: 2 dbuf x {hi plane 16K, lo plane 16K}; epilogue aliases float lm[64][68]
    __shared__ __align__(16) unsigned char smem[65536];

    const int tid  = threadIdx.x;
    const int lane = tid & 63;
    const int et   = tid >> 6;                 // wave == 16-expert tile
    const int t0   = blockIdx.x * 64;

    // staging coords: thread (sr = token row 0..15, sq = k-quad 0..15)
    const int sr = tid >> 4;
    const int sq = tid & 15;
    const unsigned swoff = (unsigned)((sr * 128 + sq * 8) ^ ((sr & 7) << 4));
    const float* xbase = x + (size_t)(t0 + sr) * DIM + sq * 4;

    // compute-side swizzled read offsets (ks even / odd)
    const unsigned roff_e = (unsigned)((((lane & 15) * 128) | ((lane >> 4) << 4))
                                       ^ ((lane & 7) << 4));
    const unsigned roff_o = roff_e ^ 64u;

    f32x4 accP[4], accQ[4];
#pragma unroll
    for (int tt = 0; tt < 4; ++tt)
#pragma unroll
        for (int j = 0; j < 4; ++j) { accP[tt][j] = 0.f; accQ[tt][j] = 0.f; }

    float4 xrA[8], xrB[8];                     // depth-2 x prefetch banks
    short8 Bh0[4], Bl0[4], Bh1[4], Bl1[4];

#define LOADX(bank_, c_) { _Pragma("unroll") for (int tt = 0; tt < 4; ++tt) \
    _Pragma("unroll") for (int i = 0; i < 2; ++i) \
        xr##bank_[tt*2+i] = *(const float4*)(xbase + (size_t)tt * 16 * DIM + (c_) * CHUNK + i * 64); }

#define BLOAD(bk_, c_) { _Pragma("unroll") for (int ksg = 0; ksg < 4; ++ksg) { \
        size_t o_ = (((size_t)et * 64 + ((c_) * 4 + ksg)) * 64 + lane) * 8; \
        Bh##bk_[ksg] = *(const short8*)(wph + o_); \
        Bl##bk_[ksg] = *(const short8*)(wpl + o_); } }

// truncation split: hi = top16(x), lo = top16(x - hi)
#define CVT_STORE(bank_, buf_) { _Pragma("unroll") for (int tt = 0; tt < 4; ++tt) \
    _Pragma("unroll") for (int i = 0; i < 2; ++i) { \
        float4 v_ = xr##bank_[tt*2+i]; \
        unsigned u0 = __float_as_uint(v_.x), u1 = __float_as_uint(v_.y); \
        unsigned u2 = __float_as_uint(v_.z), u3 = __float_as_uint(v_.w); \
        float l0 = v_.x - __uint_as_float(u0 & 0xffff0000u); \
        float l1 = v_.y - __uint_as_float(u1 & 0xffff0000u); \
        float l2 = v_.z - __uint_as_float(u2 & 0xffff0000u); \
        float l3 = v_.w - __uint_as_float(u3 & 0xffff0000u); \
        ushort4 hv_ = make_ushort4((unsigned short)(u0 >> 16), (unsigned short)(u1 >> 16), \
                                   (unsigned short)(u2 >> 16), (unsigned short)(u3 >> 16)); \
        ushort4 lv_ = make_ushort4((unsigned short)(__float_as_uint(l0) >> 16), \
                                   (unsigned short)(__float_as_uint(l1) >> 16), \
                                   (unsigned short)(__float_as_uint(l2) >> 16), \
                                   (unsigned short)(__float_as_uint(l3) >> 16)); \
        unsigned char* p_ = smem + (buf_) * 32768 + (tt*2+i) * 2048 + swoff; \
        *(ushort4*)p_ = hv_; \
        *(ushort4*)(p_ + 16384) = lv_; } }

#define MFMA_PHASE(buf_, bk_) { _Pragma("unroll") for (int ks = 0; ks < 4; ++ks) { \
        const unsigned ro_ = (ks & 1) ? roff_o : roff_e; \
        _Pragma("unroll") for (int tt = 0; tt < 4; ++tt) { \
            const unsigned char* pa_ = smem + (buf_) * 32768 + tt * 4096 + (ks >> 1) * 2048 + ro_; \
            short8 Ah_ = *(const short8*)pa_; \
            short8 Al_ = *(const short8*)(pa_ + 16384); \
            accP[tt] = __builtin_amdgcn_mfma_f32_16x16x32_bf16(Ah_, Bh##bk_[ks], accP[tt], 0, 0, 0); \
            accQ[tt] = __builtin_amdgcn_mfma_f32_16x16x32_bf16(Ah_, Bl##bk_[ks], accQ[tt], 0, 0, 0); \
            accQ[tt] = __builtin_amdgcn_mfma_f32_16x16x32_bf16(Al_, Bh##bk_[ks], accQ[tt], 0, 0, 0); } } }

// T3/T4: LDS-only wait + raw barrier -> global prefetches stay in flight
#define BARSYNC { asm volatile("s_waitcnt lgkmcnt(0)" ::: "memory"); \
                  __builtin_amdgcn_sched_barrier(0); \
                  __builtin_amdgcn_s_barrier(); }

    // prologue: chunks 0,1 in flight; chunk 0 staged; B(0) in bank 0
    LOADX(A, 0)
    LOADX(B, 1)
    BLOAD(0, 0)
    CVT_STORE(A, 0)
    BARSYNC

    // steady state: c = 0..13, branch-free bodies (7 even/odd pairs)
#pragma unroll 1
    for (int cc = 0; cc < 7; ++cc) {
        const int c0 = 2 * cc;                 // even chunk, c0 <= 12
        LOADX(A, c0 + 2)
        BLOAD(1, c0 + 1)
        MFMA_PHASE(0, 0)
        CVT_STORE(B, 1)
        BARSYNC
        const int c1 = c0 + 1;                 // odd chunk, c1 <= 13
        LOADX(B, c1 + 2)
        BLOAD(0, c1 + 1)
        MFMA_PHASE(1, 1)
        CVT_STORE(A, 0)
        BARSYNC
    }
    // tail c = 14: no LOADX
    BLOAD(1, 15)
    MFMA_PHASE(0, 0)
    CVT_STORE(B, 1)
    BARSYNC
    // tail c = 15: MFMA only (reads buf1; merge below writes buf0 region - disjoint)
    MFMA_PHASE(1, 1)

#undef LOADX
#undef BLOAD
#undef CVT_STORE
#undef MFMA_PHASE
#undef BARSYNC

    // merge logits into aliased LDS (buf0 region last read before previous barrier)
    float* lmf = (float*)smem;                 // [64][68]
#pragma unroll
    for (int tt = 0; tt < 4; ++tt)
#pragma unroll
        for (int jr = 0; jr < 4; ++jr)
            lmf[(tt * 16 + (lane >> 4) * 4 + jr) * 68 + et * 16 + (lane & 15)] =
                accP[tt][jr] + accQ[tt][jr];
    __syncthreads();

    // ---- epilogue: 4 threads per token, 16 experts each ----
    float* mout = out;
    float* wout = out + (size_t)NT * NE;
    float* iout = wout + (size_t)NT * 2;

    const int t   = tid >> 2;                  // local token 0..63
    const int s   = tid & 3;                   // 16-expert segment
    const int tok = t0 + t;

    float vv[16];
#pragma unroll
    for (int j4 = 0; j4 < 4; ++j4) {
        float4 pv = *(const float4*)&lmf[t * 68 + s * 16 + j4 * 4];
        vv[j4 * 4] = pv.x; vv[j4 * 4 + 1] = pv.y; vv[j4 * 4 + 2] = pv.z; vv[j4 * 4 + 3] = pv.w;
    }

    float m1 = -FLT_MAX, m2 = -FLT_MAX, m3 = -FLT_MAX;
    int   i1 = NE, i2 = NE, i3 = NE;
    auto ins = [&](float v, int e) {
        bool b1 = (v > m1) || (v == m1 && e < i1);
        bool b2 = (v > m2) || (v == m2 && e < i2);
        bool b3 = (v > m3) || (v == m3 && e < i3);
        if (b1)      { m3 = m2; i3 = i2; m2 = m1; i2 = i1; m1 = v; i1 = e; }
        else if (b2) { m3 = m2; i3 = i2; m2 = v; i2 = e; }
        else if (b3) { m3 = v; i3 = e; }
    };
#pragma unroll
    for (int j = 0; j < 16; ++j) ins(vv[j], s * 16 + j);
#pragma unroll
    for (int off = 1; off <= 2; off <<= 1) {   // merge across the 4-lane group
        float om1 = __shfl_xor(m1, off, 64); int oi1 = __shfl_xor(i1, off, 64);
        float om2 = __shfl_xor(m2, off, 64); int oi2 = __shfl_xor(i2, off, 64);
        float om3 = __shfl_xor(m3, off, 64); int oi3 = __shfl_xor(i3, off, 64);
        ins(om1, oi1); ins(om2, oi2); ins(om3, oi3);
    }

    float ed  = expf(m2 - m1);
    float inv = 1.f / (1.f + ed);

#pragma unroll
    for (int j4 = 0; j4 < 4; ++j4) {
        float4 mv;
        int e0 = s * 16 + j4 * 4;
        mv.x = (e0     == i1 || e0     == i2) ? 1.f : 0.f;
        mv.y = (e0 + 1 == i1 || e0 + 1 == i2) ? 1.f : 0.f;
        mv.z = (e0 + 2 == i1 || e0 + 2 == i2) ? 1.f : 0.f;
        mv.w = (e0 + 3 == i1 || e0 + 3 == i2) ? 1.f : 0.f;
        *(float4*)(mout + (size_t)tok * NE + e0) = mv;
    }

    if (s == 0) {
        *(float2*)(wout + 2 * tok) = make_float2(inv, ed * inv);
        *(float2*)(iout + 2 * tok) = make_float2((float)i1, (float)i2);
        if ((m1 - m2 < TAU) || (m2 - m3 < TAU)) {
            int slot = atomicAdd(cnt, 1);
            list[slot] = tok;
        }
    }
}

// Exact fp32 recompute of flagged (near-tie) tokens; overwrites their outputs.
__global__ __launch_bounds__(256)
void repair(const float* __restrict__ x, const float* __restrict__ gw,
            float* __restrict__ out, const int* __restrict__ cnt,
            const int* __restrict__ list) {
    __shared__ float red[64][5];
    const int n   = *cnt;
    const int tid = threadIdx.x;
    const int e   = tid & 63, qq = tid >> 6;     // expert, k-quarter

    float* mout = out;
    float* wout = out + (size_t)NT * NE;
    float* iout = wout + (size_t)NT * 2;

    for (int i = blockIdx.x; i < n; i += gridDim.x) {
        const int tok = list[i];
        const float* xr = x + (size_t)tok * DIM + qq * 512;
        const float* wr = gw + (size_t)e * DIM + qq * 512;
        float a = 0.f;
        for (int j = 0; j < 512; j += 4) {
            float4 xv = *(const float4*)(xr + j);
            float4 wv = *(const float4*)(wr + j);
            a = fmaf(xv.x, wv.x, a); a = fmaf(xv.y, wv.y, a);
            a = fmaf(xv.z, wv.z, a); a = fmaf(xv.w, wv.w, a);
        }
        red[e][qq] = a;
        __syncthreads();
        if (tid < 64) {
            float v = ((red[e][0] + red[e][1]) + red[e][2]) + red[e][3];
            float m1 = v, m2 = -FLT_MAX; int i1 = e, i2 = NE;
#pragma unroll
            for (int off = 1; off <= 32; off <<= 1) {
                float om1 = __shfl_xor(m1, off, 64); int oi1 = __shfl_xor(i1, off, 64);
                float om2 = __shfl_xor(m2, off, 64); int oi2 = __shfl_xor(i2, off, 64);
                bool selfFirst = (m1 > om1) || (m1 == om1 && i1 < oi1);
                if (selfFirst) {
                    if (!((m2 > om1) || (m2 == om1 && i2 < oi1))) { m2 = om1; i2 = oi1; }
                } else {
                    bool c = (m1 > om2) || (m1 == om2 && i1 < oi2);
                    if (c) { m2 = m1; i2 = i1; } else { m2 = om2; i2 = oi2; }
                    m1 = om1; i1 = oi1;
                }
            }
            float ed  = expf(m2 - m1);
            float inv = 1.f / (1.f + ed);
            mout[(size_t)tok * NE + e] = (e == i1 || e == i2) ? 1.f : 0.f;
            if (e == 0) {
                *(float2*)(wout + 2 * tok) = make_float2(inv, ed * inv);
                *(float2*)(iout + 2 * tok) = make_float2((float)i1, (float)i2);
            }
        }
        __syncthreads();
    }
}

extern "C" void kernel_launch(void* const* d_in, const int* in_sizes, int n_in,
                              void* d_out, int out_size, void* d_ws, size_t ws_size,
                              hipStream_t stream) {
    const float* x  = (const float*)d_in[0];
    const float* gw = (const float*)d_in[1];
    float* out = (float*)d_out;

    unsigned short* wph = (unsigned short*)d_ws;         // 256 KB (packed hi)
    unsigned short* wpl = wph + (size_t)NE * DIM;        // 256 KB (packed lo)
    int* cnt  = (int*)(wpl + (size_t)NE * DIM);          // 4 B
    int* list = cnt + 1;                                 // 128 KB

    prep_w<<<dim3(64), dim3(256), 0, stream>>>(gw, wph, wpl, cnt);
    router_mfma<<<dim3(NT / 64), dim3(256), 0, stream>>>(x, wph, wpl, out, cnt, list);
    repair<<<dim3(256), dim3(256), 0, stream>>>(x, gw, out, cnt, list);
}